// Round 1
// baseline (2676.132 us; speedup 1.0000x reference)
//
#include <hip/hip_runtime.h>

#define NT 512
#define TRAJ 4

constexpr int Lk = 200;
constexpr int NSTEPS = 100;

// Stable softplus, matches jax.nn.softplus in fp32: max(x,0) + log1p(exp(-|x|))
__device__ __forceinline__ float sp_act(float x) {
    return fmaxf(x, 0.0f) + log1pf(expf(-fabsf(x)));
}

// fW3 [2048][128] -> fW3T [128][2048] in workspace (coalesced writes, once per launch)
__global__ void fw3_transpose(const float* __restrict__ w, float* __restrict__ wT) {
    int idx = blockIdx.x * 256 + threadIdx.x;   // 0 .. 262143
    int k = idx >> 11;        // 0..127
    int n = idx & 2047;       // 0..2047
    wT[idx] = w[n * 128 + k];
}

// Stage global weight W[O][I] (row-major) into LDS transposed T[I][O].
template<int O, int I>
__device__ __forceinline__ void stage_T(const float* __restrict__ g, float* __restrict__ T) {
    for (int base = threadIdx.x * 4; base < O * I; base += NT * 4) {
        const float4 w = *(const float4*)(g + base);
        const int o = base / I;
        const int i = base % I;
        T[(i + 0) * O + o] = w.x;
        T[(i + 1) * O + o] = w.y;
        T[(i + 2) * O + o] = w.z;
        T[(i + 3) * O + o] = w.w;
    }
}

// out[t][o] = act(bias[o] + sum_i in[t][i] * T[i][o])  for t in [0,TRAJ), o in [0,O)
// ACT: 0=none, 1=softplus, 2=relu. T in LDS, conflict-free (lanes read consecutive o).
template<int I, int O, int ACT>
__device__ __forceinline__ void mlp_layer(const float* __restrict__ T,
                                          const float* __restrict__ bias,
                                          const float* __restrict__ in, int inStride,
                                          float* __restrict__ out, int outStride) {
    const int tid = threadIdx.x;
    constexpr int TOT = TRAJ * O;
    for (int e = tid; e < TOT; e += NT) {
        const int t = e / O;
        const int o = e % O;
        const float* inr = in + t * inStride;
        float acc = bias[o];
        #pragma unroll 4
        for (int i = 0; i < I; ++i) acc = fmaf(inr[i], T[i * O + o], acc);
        if (ACT == 1) acc = sp_act(acc);
        else if (ACT == 2) acc = fmaxf(acc, 0.0f);
        out[t * outStride + o] = acc;
    }
}

// One vector-field eval: kout[t][h] = sum_d (fW3 @ sp(fW2 @ sp(fW1 @ y + b1) + b2) + b3)[t, h*32+d] * dX[t][d]
__device__ __forceinline__ void evalvf(float t,
                                       const float* __restrict__ yin,     // LDS [TRAJ][64]
                                       float* __restrict__ kout,          // LDS [TRAJ][64]
                                       const float* __restrict__ wT1,     // LDS [64][128]
                                       const float* __restrict__ wT2,     // LDS [128][128]
                                       const float* __restrict__ fb1s,
                                       const float* __restrict__ fb2s,
                                       float* __restrict__ h1s,           // LDS [TRAJ][128]
                                       float* __restrict__ h2s,           // LDS [TRAJ][128]
                                       float* __restrict__ dXs,           // LDS [TRAJ][32]
                                       const float* __restrict__ ts,
                                       const float* __restrict__ coef_b,
                                       const float* __restrict__ coef_c,
                                       const float* __restrict__ coef_d,
                                       int bbase,
                                       const float4* __restrict__ wp,     // fW3T base (float4) + tid
                                       float4 fb3r)
{
    const int tid = threadIdx.x;

    // cubic-spline derivative dX/dt at scalar time t (i = clip(floor(t),0,L-2), ts = arange)
    if (tid < TRAJ * 32) {
        int i = (int)floorf(t);
        i = min(max(i, 0), Lk - 2);
        const float frac = t - ts[i];
        const int tt = tid >> 5, d = tid & 31;
        const size_t off = ((size_t)(bbase + tt) * 199 + (size_t)i) * 32 + d;
        dXs[tid] = coef_b[off] + frac * (2.0f * coef_c[off] + 3.0f * frac * coef_d[off]);
    }
    mlp_layer<64, 128, 1>(wT1, fb1s, yin, 64, h1s, 128);
    __syncthreads();
    mlp_layer<128, 128, 1>(wT2, fb2s, h1s, 128, h2s, 128);
    __syncthreads();

    // Big layer: thread owns n = 4*tid + j (j=0..3). g[t][n] = fW3[n,:] . h2[t,:] + fb3[n].
    float4 acc[TRAJ];
    #pragma unroll
    for (int t4 = 0; t4 < TRAJ; ++t4) acc[t4] = make_float4(0.f, 0.f, 0.f, 0.f);

    for (int k0 = 0; k0 < 128; k0 += 4) {
        const float4 w0 = wp[(k0 + 0) * 512];
        const float4 w1 = wp[(k0 + 1) * 512];
        const float4 w2 = wp[(k0 + 2) * 512];
        const float4 w3 = wp[(k0 + 3) * 512];
        #pragma unroll
        for (int t4 = 0; t4 < TRAJ; ++t4) {
            const float4 h = *(const float4*)(h2s + t4 * 128 + k0);
            float4 a = acc[t4];
            a.x = fmaf(h.x, w0.x, a.x); a.y = fmaf(h.x, w0.y, a.y); a.z = fmaf(h.x, w0.z, a.z); a.w = fmaf(h.x, w0.w, a.w);
            a.x = fmaf(h.y, w1.x, a.x); a.y = fmaf(h.y, w1.y, a.y); a.z = fmaf(h.y, w1.z, a.z); a.w = fmaf(h.y, w1.w, a.w);
            a.x = fmaf(h.z, w2.x, a.x); a.y = fmaf(h.z, w2.y, a.y); a.z = fmaf(h.z, w2.z, a.z); a.w = fmaf(h.z, w2.w, a.w);
            a.x = fmaf(h.w, w3.x, a.x); a.y = fmaf(h.w, w3.y, a.y); a.z = fmaf(h.w, w3.z, a.z); a.w = fmaf(h.w, w3.w, a.w);
            acc[t4] = a;
        }
    }

    // einsum over d: n = 4*tid+j => h = tid>>3, d = 4*(tid&7)+j. Reduce over the 8 lanes of each h.
    const int dbase = 4 * (tid & 7);
    float part[TRAJ];
    #pragma unroll
    for (int t4 = 0; t4 < TRAJ; ++t4) {
        const float4 dx = *(const float4*)(dXs + t4 * 32 + dbase);
        part[t4] = (acc[t4].x + fb3r.x) * dx.x + (acc[t4].y + fb3r.y) * dx.y +
                   (acc[t4].z + fb3r.z) * dx.z + (acc[t4].w + fb3r.w) * dx.w;
    }
    #pragma unroll
    for (int m = 1; m < 8; m <<= 1) {
        #pragma unroll
        for (int t4 = 0; t4 < TRAJ; ++t4) part[t4] += __shfl_xor(part[t4], m, 64);
    }
    if ((tid & 7) == 0) {
        const int h = tid >> 3;
        #pragma unroll
        for (int t4 = 0; t4 < TRAJ; ++t4) kout[t4 * 64 + h] = part[t4];
    }
    __syncthreads();
}

__global__ __launch_bounds__(NT, 1)
void cde_kernel(const float* __restrict__ ts,
                const float* __restrict__ coef_d, const float* __restrict__ coef_c,
                const float* __restrict__ coef_b, const float* __restrict__ coef_a,
                const float* __restrict__ iW1, const float* __restrict__ ib1,
                const float* __restrict__ iW2, const float* __restrict__ ib2,
                const float* __restrict__ iW3, const float* __restrict__ ib3,
                const float* __restrict__ fW1, const float* __restrict__ fb1,
                const float* __restrict__ fW2, const float* __restrict__ fb2,
                const float* __restrict__ fb3,
                const float* __restrict__ dW1, const float* __restrict__ db1,
                const float* __restrict__ dW2, const float* __restrict__ db2,
                const float* __restrict__ dW3, const float* __restrict__ db3,
                const float* __restrict__ fW3T,
                float* __restrict__ outp)
{
    // weight region is a union across phases: init (112KB) / main (96KB) / decoder (104KB)
    __shared__ float wreg[28672];
    __shared__ float h1s[TRAJ * 128], h2s[TRAJ * 128];
    __shared__ float ys[TRAJ * 64], ys2[TRAJ * 64], k1s[TRAJ * 64], k2s[TRAJ * 64];
    __shared__ float dXs[TRAJ * 32], a0s[TRAJ * 32];
    __shared__ float fb1s[128], fb2s[128];

    const int tid = threadIdx.x;
    const int bbase = blockIdx.x * TRAJ;

    const float ts0 = ts[0];
    const float dt = (ts[Lk - 1] - ts0) / (float)NSTEPS;
    const float4 fb3r = *((const float4*)fb3 + tid);         // n = 4*tid .. 4*tid+3
    const float4* wp = (const float4*)fW3T + tid;

    // ---- initial condition: y0 = sp(MLP_i(coef_a[:,0,:])) ----
    if (tid < TRAJ * 32) {
        const int t = tid >> 5, d = tid & 31;
        a0s[t * 32 + d] = coef_a[((size_t)(bbase + t) * 199) * 32 + d];
    }
    stage_T<128, 32>(iW1, wreg);                       // iT1 [32][128]
    stage_T<128, 128>(iW2, wreg + 32 * 128);           // iT2 [128][128]
    stage_T<64, 128>(iW3, wreg + 32 * 128 + 128 * 128);// iT3 [128][64]
    if (tid < 128) { fb1s[tid] = fb1[tid]; fb2s[tid] = fb2[tid]; }
    __syncthreads();
    mlp_layer<32, 128, 1>(wreg, ib1, a0s, 32, h1s, 128);
    __syncthreads();
    mlp_layer<128, 128, 1>(wreg + 32 * 128, ib2, h1s, 128, h2s, 128);
    __syncthreads();
    mlp_layer<128, 64, 1>(wreg + 32 * 128 + 128 * 128, ib3, h2s, 128, ys, 64);
    __syncthreads();

    // ---- stage vector-field small weights (resident for all 200 evals) ----
    stage_T<128, 64>(fW1, wreg);                       // wT1 [64][128]
    stage_T<128, 128>(fW2, wreg + 64 * 128);           // wT2 [128][128]
    __syncthreads();

    // ---- Heun over 100 fixed steps ----
    for (int step = 0; step < NSTEPS; ++step) {
        const float t1 = ts0 + (float)step * dt;
        evalvf(t1, ys, k1s, wreg, wreg + 64 * 128, fb1s, fb2s, h1s, h2s, dXs,
               ts, coef_b, coef_c, coef_d, bbase, wp, fb3r);
        if (tid < TRAJ * 64) ys2[tid] = ys[tid] + dt * k1s[tid];
        __syncthreads();
        evalvf(t1 + dt, ys2, k2s, wreg, wreg + 64 * 128, fb1s, fb2s, h1s, h2s, dXs,
               ts, coef_b, coef_c, coef_d, bbase, wp, fb3r);
        if (tid < TRAJ * 64) ys[tid] += 0.5f * dt * (k1s[tid] + k2s[tid]);
        __syncthreads();
    }

    // ---- decoder: Linear->relu->Linear->relu->Linear ----
    stage_T<128, 64>(dW1, wreg);                          // dT1 [64][128]
    stage_T<128, 128>(dW2, wreg + 64 * 128);              // dT2 [128][128]
    stage_T<16, 128>(dW3, wreg + 64 * 128 + 128 * 128);   // dT3 [128][16]
    __syncthreads();
    mlp_layer<64, 128, 2>(wreg, db1, ys, 64, h1s, 128);
    __syncthreads();
    mlp_layer<128, 128, 2>(wreg + 64 * 128, db2, h1s, 128, h2s, 128);
    __syncthreads();
    mlp_layer<128, 16, 0>(wreg + 64 * 128 + 128 * 128, db3, h2s, 128,
                          outp + (size_t)bbase * 16, 16);
}

extern "C" void kernel_launch(void* const* d_in, const int* in_sizes, int n_in,
                              void* d_out, int out_size, void* d_ws, size_t ws_size,
                              hipStream_t stream) {
    (void)in_sizes; (void)n_in; (void)out_size; (void)ws_size;
    const float* ts     = (const float*)d_in[0];
    const float* coef_d = (const float*)d_in[1];
    const float* coef_c = (const float*)d_in[2];
    const float* coef_b = (const float*)d_in[3];
    const float* coef_a = (const float*)d_in[4];
    const float* iW1 = (const float*)d_in[5];  const float* ib1 = (const float*)d_in[6];
    const float* iW2 = (const float*)d_in[7];  const float* ib2 = (const float*)d_in[8];
    const float* iW3 = (const float*)d_in[9];  const float* ib3 = (const float*)d_in[10];
    const float* fW1 = (const float*)d_in[11]; const float* fb1 = (const float*)d_in[12];
    const float* fW2 = (const float*)d_in[13]; const float* fb2 = (const float*)d_in[14];
    const float* fW3 = (const float*)d_in[15]; const float* fb3 = (const float*)d_in[16];
    const float* dW1 = (const float*)d_in[17]; const float* db1 = (const float*)d_in[18];
    const float* dW2 = (const float*)d_in[19]; const float* db2 = (const float*)d_in[20];
    const float* dW3 = (const float*)d_in[21]; const float* db3 = (const float*)d_in[22];

    float* fW3T = (float*)d_ws;   // 1 MB: fW3 transposed to [128][2048]

    fw3_transpose<<<1024, 256, 0, stream>>>(fW3, fW3T);
    cde_kernel<<<256, NT, 0, stream>>>(ts, coef_d, coef_c, coef_b, coef_a,
                                       iW1, ib1, iW2, ib2, iW3, ib3,
                                       fW1, fb1, fW2, fb2, fb3,
                                       dW1, db1, dW2, db2, dW3, db3,
                                       fW3T, (float*)d_out);
}